// Round 6
// baseline (259.273 us; speedup 1.0000x reference)
//
#include <hip/hip_runtime.h>

typedef unsigned short ushort_t;
using f32x4  = __attribute__((ext_vector_type(4))) float;
using bf16x8 = __attribute__((ext_vector_type(8))) short;
using u16x8  = __attribute__((ext_vector_type(8))) unsigned short;
using h2v    = __attribute__((ext_vector_type(2))) _Float16;

constexpr int Bc = 4;
constexpr int Nc = 512;
constexpr int Dc = 512;
constexpr int Pc = 128;
constexpr int ROWS = Bc * Nc;   // 2048

__device__ inline unsigned short f2bf(float f) {
    unsigned u = __builtin_bit_cast(unsigned, f);
    unsigned r = u + 0x7fffu + ((u >> 16) & 1u);   // RNE
    return (unsigned short)(r >> 16);
}

__device__ inline void gload_lds16(const void* g, void* l) {
    __builtin_amdgcn_global_load_lds(
        (const __attribute__((address_space(1))) unsigned int*)g,
        (__attribute__((address_space(3))) unsigned int*)l, 16, 0, 0);
}

__device__ inline unsigned packh2(float a, float b) {
    unsigned short lo = __builtin_bit_cast(unsigned short, (_Float16)a);
    unsigned short hi = __builtin_bit_cast(unsigned short, (_Float16)b);
    return (unsigned)lo | ((unsigned)hi << 16);
}

// Software grid barrier: all 512 blocks co-resident (grid = 2 blocks/CU,
// __launch_bounds__(256,2)). Agent-scope fences for cross-XCD visibility.
__device__ inline void grid_barrier(unsigned* ctr, unsigned target) {
    __threadfence();               // release: drain this thread's stores
    __syncthreads();
    if (threadIdx.x == 0) {
        __hip_atomic_fetch_add(ctr, 1u, __ATOMIC_RELEASE, __HIP_MEMORY_SCOPE_AGENT);
        while (__hip_atomic_load(ctr, __ATOMIC_ACQUIRE, __HIP_MEMORY_SCOPE_AGENT) < target)
            __builtin_amdgcn_s_sleep(2);
    }
    __syncthreads();
    __threadfence();               // acquire side
}

// ---------------------------------------------------------------------------
// Fused kernel: 512 blocks x 256 threads, 3 phases, 2 grid barriers.
//  P0: input fp32 -> inBF2 (frag-ordered bf16); W -> WcatT2 (blocks<64).
//  P1: proj GEMM [2048,512]@[512,512]: 512 units of 32r x 64c, MFMA 16x16x32.
//      ny 0..3 -> leftH/rightH (f16); ny 4..7 -> start/end partials -> parts.
//  P2: bigram via packed-f16 dot2; blocks<32 also combine start/end.
// ---------------------------------------------------------------------------
__global__ __launch_bounds__(256, 2) void fused_kernel(
    const float* __restrict__ input,
    const float* __restrict__ Wl,  const float* __restrict__ bl,
    const float* __restrict__ Wr,
    const float* __restrict__ Wo,  const float* __restrict__ bo,
    const float* __restrict__ Ws1, const float* __restrict__ bs1,
    const float* __restrict__ Ws2, const float* __restrict__ bs2,
    const float* __restrict__ We1, const float* __restrict__ be1,
    const float* __restrict__ We2, const float* __restrict__ be2,
    ushort_t* __restrict__ leftH, ushort_t* __restrict__ rightH,
    float* __restrict__ parts,
    ushort_t* __restrict__ inBF2, ushort_t* __restrict__ WcatT2,
    unsigned* __restrict__ ctr,
    float* __restrict__ out, float* __restrict__ start_out,
    float* __restrict__ end_out)
{
    __shared__ alignas(16) unsigned char SMEM[26368];
    const int bx = blockIdx.x, t = threadIdx.x;

    // ================= Phase 0: convert =================
    {
        const int mt = bx >> 4, ks = (bx >> 1) & 7, hh = bx & 1;
        const int c = t & 7, r = (t >> 3) + hh * 32;
        const float* s = input + (size_t)(mt * 64 + r) * Dc + ks * 64 + c * 8;
        float4 v0 = *(const float4*)s;
        float4 v1 = *(const float4*)(s + 4);
        u16x8 o;
        o[0] = f2bf(v0.x); o[1] = f2bf(v0.y); o[2] = f2bf(v0.z); o[3] = f2bf(v0.w);
        o[4] = f2bf(v1.x); o[5] = f2bf(v1.y); o[6] = f2bf(v1.z); o[7] = f2bf(v1.w);
        *(u16x8*)(inBF2 + ((size_t)(mt * 8 + ks) * 8 + c) * 512 + r * 8) = o;
    }
    if (bx < 64) {
        // W transpose-convert: unit (nt, ks)
        float (*T)[68] = (float(*)[68])SMEM;
        const int nt = bx >> 3, ks = bx & 7;
        const int mi = nt >> 1, cm0 = (nt & 1) * 64;
        const float* Wm = (mi == 0) ? Wl : (mi == 1) ? Wr : (mi == 2) ? Ws1 : We1;
        const int kk_ = t >> 4, cc = (t & 15) << 2;
        #pragma unroll
        for (int u = 0; u < 4; ++u)
            *(float4*)&T[kk_ + 16 * u][cc] =
                *(const float4*)&Wm[(size_t)(ks * 64 + kk_ + 16 * u) * Pc + cm0 + cc];
        __syncthreads();
        const int col = t & 63, c2 = t >> 6;
        #pragma unroll
        for (int h = 0; h < 2; ++h) {
            const int kc = c2 + h * 4;
            u16x8 o;
            #pragma unroll
            for (int i = 0; i < 8; ++i) o[i] = f2bf(T[kc * 8 + i][col]);
            *(u16x8*)(WcatT2 + ((size_t)(nt * 8 + ks) * 8 + kc) * 512 + col * 8) = o;
        }
    }

    grid_barrier(ctr, 512);

    // ================= Phase 1: proj MFMA =================
    {
        const int mt2 = bx >> 3, ny = bx & 7;
        const int row0 = mt2 * 32;
        const int w = t >> 6, l = t & 63;
        const int wm = w & 1, wn = w >> 1;
        const int fr = l & 15, fg = l >> 4;

        ushort_t* As = (ushort_t*)SMEM;            // [2][2048]
        ushort_t* Bs = (ushort_t*)(SMEM + 8192);   // [2][4096]
        float*    red = (float*)(SMEM + 24576);    // [64]

        const ushort_t* Atile = inBF2 + (size_t)(mt2 >> 1) * 8 * 4096;
        const int h32 = (mt2 & 1) * 32;
        const ushort_t* Bbase = WcatT2 + (size_t)ny * 8 * 4096;

        f32x4 acc0 = {0.f, 0.f, 0.f, 0.f}, acc1 = {0.f, 0.f, 0.f, 0.f};

#define PSTAGE(BI, KS)                                                         \
    {                                                                          \
        const ushort_t* ga = Atile + (KS) * 4096;                              \
        const ushort_t* gb = Bbase + (KS) * 4096;                              \
        gload_lds16(ga + (2 * w + (l >> 5)) * 512 + (h32 + (l & 31)) * 8,      \
                    As + (BI) * 2048 + w * 512);                               \
        gload_lds16(gb + w * 512 + l * 8, Bs + (BI) * 4096 + w * 512);         \
        gload_lds16(gb + (w + 4) * 512 + l * 8,                                \
                    Bs + (BI) * 4096 + (w + 4) * 512);                         \
    }

        PSTAGE(0, 0);
        __syncthreads();

        for (int ks = 0; ks < 8; ++ks) {
            const int bi = ks & 1;
            if (ks < 7) PSTAGE(bi ^ 1, ks + 1);
            #pragma unroll
            for (int kk = 0; kk < 2; ++kk) {
                const int kc = kk * 4 + fg;
                bf16x8 a  = *(const bf16x8*)(As + bi * 2048 + kc * 256 + (wm * 16 + fr) * 8);
                bf16x8 b0 = *(const bf16x8*)(Bs + bi * 4096 + kc * 512 + (wn * 32 + fr) * 8);
                bf16x8 b1 = *(const bf16x8*)(Bs + bi * 4096 + kc * 512 + (wn * 32 + 16 + fr) * 8);
                acc0 = __builtin_amdgcn_mfma_f32_16x16x32_bf16(a, b0, acc0, 0, 0, 0);
                acc1 = __builtin_amdgcn_mfma_f32_16x16x32_bf16(a, b1, acc1, 0, 0, 0);
            }
            __syncthreads();
        }
#undef PSTAGE

        const int fq4 = fg << 2;
        if (ny < 4) {
            ushort_t* outp = (ny < 2) ? leftH : rightH;
            const int cb = (ny & 1) * 64 + wn * 32;
            #pragma unroll
            for (int n = 0; n < 2; ++n) {
                const int col = cb + n * 16 + fr;
                const float bv = (ny < 2) ? bl[col] : 0.f;
                const f32x4 av = n ? acc1 : acc0;
                #pragma unroll
                for (int q = 0; q < 4; ++q) {
                    float v = av[q] + bv;
                    outp[(size_t)(row0 + wm * 16 + fq4 + q) * Pc + col] =
                        __builtin_bit_cast(ushort_t, (_Float16)v);
                }
            }
        } else {
            const int pi = ny - 4;
            const float* b1 = (ny < 6) ? bs1 : be1;
            const float* W2 = (ny < 6) ? Ws2 : We2;
            const int pb = (pi & 1) * 64;
            #pragma unroll
            for (int q = 0; q < 4; ++q) {
                const int cp0 = pb + wn * 32 + fr;
                const int cp1 = pb + wn * 32 + 16 + fr;
                float v = fmaxf(acc0[q] + b1[cp0], 0.f) * W2[cp0]
                        + fmaxf(acc1[q] + b1[cp1], 0.f) * W2[cp1];
                v += __shfl_xor(v, 1);
                v += __shfl_xor(v, 2);
                v += __shfl_xor(v, 4);
                v += __shfl_xor(v, 8);
                if (fr == 0) red[wn * 32 + wm * 16 + fq4 + q] = v;
            }
            __syncthreads();
            if (t < 32) parts[pi * ROWS + row0 + t] = red[t] + red[32 + t];
        }
    }

    grid_barrier(ctr, 1024);

    // ================= Phase 2: bigram =================
    if (bx < 32) {
        const int base = bx * 64;
        if (t < 64) {
            const int r = base + t;
            start_out[r] = parts[r] + parts[ROWS + r] + bs2[0];
        } else if (t < 128) {
            const int r = base + t - 64;
            end_out[r] = parts[2 * ROWS + r] + parts[3 * ROWS + r] + be2[0];
        }
    }
    {
        const int b = bx >> 7, it = (bx >> 4) & 7, jt = bx & 15;

        unsigned (*Lh)[68] = (unsigned(*)[68])SMEM;            // 32 rows
        unsigned (*Rh)[68] = (unsigned(*)[68])(SMEM + 8704);   // 64 rows
        unsigned* woh      = (unsigned*)(SMEM + 26112);        // 64

        const ushort_t* lp = leftH  + (size_t)(b * Nc + jt * 32) * Pc;
        const ushort_t* rp = rightH + (size_t)(b * Nc + it * 64) * Pc;

        #pragma unroll
        for (int u = 0; u < 2; ++u) {
            int f = t + u * 256, r = f >> 4, c = f & 15;
            *(float4*)&Lh[r][c * 4] = *(const float4*)(lp + (size_t)r * Pc + c * 8);
        }
        #pragma unroll
        for (int u = 0; u < 4; ++u) {
            int f = t + u * 256, r = f >> 4, c = f & 15;
            *(float4*)&Rh[r][c * 4] = *(const float4*)(rp + (size_t)r * Pc + c * 8);
        }
        if (t < 64) woh[t] = packh2(Wo[2 * t], Wo[2 * t + 1]);
        __syncthreads();

        const int jl = t & 15;   // j = jl + 16*jj, jj<2
        const int il = t >> 4;   // i = il + 16*ii, ii<4

        float acc[4][2] = {};
        const h2v hz = {(_Float16)0.f, (_Float16)0.f};

        #pragma unroll 8
        for (int s = 0; s < 32; ++s) {        // 4 p's per step
            uint2 w2 = *(const uint2*)&woh[2 * s];
            uint2 l2[2], r2[4];
            #pragma unroll
            for (int jj = 0; jj < 2; ++jj) l2[jj] = *(const uint2*)&Lh[jl + 16 * jj][2 * s];
            #pragma unroll
            for (int ii = 0; ii < 4; ++ii) r2[ii] = *(const uint2*)&Rh[il + 16 * ii][2 * s];

            #pragma unroll
            for (int h = 0; h < 2; ++h) {
                const unsigned wu = h ? w2.y : w2.x;
                h2v lv[2], rv[4];
                #pragma unroll
                for (int jj = 0; jj < 2; ++jj)
                    lv[jj] = __builtin_bit_cast(h2v, h ? l2[jj].y : l2[jj].x);
                #pragma unroll
                for (int ii = 0; ii < 4; ++ii)
                    rv[ii] = __builtin_bit_cast(h2v, h ? r2[ii].y : r2[ii].x);
                #pragma unroll
                for (int ii = 0; ii < 4; ++ii) {
                    #pragma unroll
                    for (int jj = 0; jj < 2; ++jj) {
                        h2v sum = lv[jj] + rv[ii];                       // v_pk_add_f16
                        sum = __builtin_elementwise_max(sum, hz);        // v_pk_max_f16
                        unsigned su = __builtin_bit_cast(unsigned, sum);
                        asm("v_dot2_f32_f16 %0, %1, %2, %0"
                            : "+v"(acc[ii][jj]) : "v"(su), "v"(wu));
                    }
                }
            }
        }

        const float bias = bo[0];
        #pragma unroll
        for (int ii = 0; ii < 4; ++ii) {
            #pragma unroll
            for (int jj = 0; jj < 2; ++jj) {
                const int gi = it * 64 + il + 16 * ii;
                const int gj = jt * 32 + jl + 16 * jj;
                out[((size_t)b * Nc + gi) * Nc + gj] = acc[ii][jj] + bias;
            }
        }
    }
}

extern "C" void kernel_launch(void* const* d_in, const int* in_sizes, int n_in,
                              void* d_out, int out_size, void* d_ws, size_t ws_size,
                              hipStream_t stream) {
    const float* input = (const float*)d_in[0];
    const float* Wl  = (const float*)d_in[1];
    const float* bl  = (const float*)d_in[2];
    const float* Wr  = (const float*)d_in[3];
    const float* Wo  = (const float*)d_in[4];
    const float* bo  = (const float*)d_in[5];
    const float* Ws1 = (const float*)d_in[6];
    const float* bs1 = (const float*)d_in[7];
    const float* Ws2 = (const float*)d_in[8];
    const float* bs2 = (const float*)d_in[9];
    const float* We1 = (const float*)d_in[10];
    const float* be1 = (const float*)d_in[11];
    const float* We2 = (const float*)d_in[12];
    const float* be2 = (const float*)d_in[13];

    float* out    = (float*)d_out;
    float* bigram = out;
    float* start  = out + (size_t)Bc * Nc * Nc;
    float* end    = start + (size_t)Bc * Nc;

    unsigned* ctr    = (unsigned*)d_ws;                        // 4 B (zeroed below)
    char* base       = (char*)d_ws + 256;
    ushort_t* leftH  = (ushort_t*)base;                        // 2048*128 f16
    ushort_t* rightH = leftH + (size_t)ROWS * Pc;              // 2048*128 f16
    float* parts     = (float*)(rightH + (size_t)ROWS * Pc);   // 4*2048 f32
    ushort_t* inBF2  = (ushort_t*)(parts + 4 * ROWS);          // 2048*512 bf16
    ushort_t* WcatT2 = inBF2 + (size_t)ROWS * Dc;              // 512*512 bf16

    hipMemsetAsync(ctr, 0, 4, stream);

    fused_kernel<<<512, 256, 0, stream>>>(
        input, Wl, bl, Wr, Wo, bo, Ws1, bs1, Ws2, bs2, We1, be1, We2, be2,
        leftH, rightH, parts, inBF2, WcatT2, ctr, bigram, start, end);
}

// Round 7
// 31.435 us; speedup vs baseline: 8.2480x; 8.2480x over previous
//
#include <hip/hip_runtime.h>

typedef unsigned short ushort_t;
using f32x4  = __attribute__((ext_vector_type(4))) float;
using bf16x8 = __attribute__((ext_vector_type(8))) short;
using u16x8  = __attribute__((ext_vector_type(8))) unsigned short;
using h2v    = __attribute__((ext_vector_type(2))) _Float16;

constexpr int Bc = 4;
constexpr int Nc = 512;
constexpr int Dc = 512;
constexpr int Pc = 128;
constexpr int ROWS = Bc * Nc;   // 2048

__device__ inline unsigned short f2bf(float f) {
    unsigned u = __builtin_bit_cast(unsigned, f);
    unsigned r = u + 0x7fffu + ((u >> 16) & 1u);   // RNE
    return (unsigned short)(r >> 16);
}

__device__ inline void gload_lds16(const void* g, void* l) {
    __builtin_amdgcn_global_load_lds(
        (const __attribute__((address_space(1))) unsigned int*)g,
        (__attribute__((address_space(3))) unsigned int*)l, 16, 0, 0);
}

__device__ inline unsigned packh2(float a, float b) {
    unsigned short lo = __builtin_bit_cast(unsigned short, (_Float16)a);
    unsigned short hi = __builtin_bit_cast(unsigned short, (_Float16)b);
    return (unsigned)lo | ((unsigned)hi << 16);
}

// ---------------------------------------------------------------------------
// convert (unchanged): MFMA-fragment-ordered bf16 tensors.
//   inBF2 [mt(32)][ks(8)][kc(8)][row(64)][8]
//   WcatT2[nt(8)][ks(8)][kc(8)][col(64)][8]
// ---------------------------------------------------------------------------
__global__ __launch_bounds__(256) void convert_kernel(
    const float* __restrict__ input,
    const float* __restrict__ Wl,  const float* __restrict__ Wr,
    const float* __restrict__ Ws1, const float* __restrict__ We1,
    ushort_t* __restrict__ inBF2, ushort_t* __restrict__ WcatT2)
{
    const int bx = blockIdx.x, t = threadIdx.x;
    __shared__ float T[64][68];

    if (bx < 256) {
        const int mt = bx >> 3, ks = bx & 7;
        const int c = t & 7, r0 = t >> 3;
        const float* src = input + (size_t)(mt * 64) * Dc + ks * 64;
        ushort_t* dstc = inBF2 + ((size_t)(mt * 8 + ks) * 8 + c) * 512;
        #pragma unroll
        for (int h = 0; h < 2; ++h) {
            const int r = r0 + h * 32;
            const float* s = src + (size_t)r * Dc + c * 8;
            float4 v0 = *(const float4*)s;
            float4 v1 = *(const float4*)(s + 4);
            u16x8 o;
            o[0] = f2bf(v0.x); o[1] = f2bf(v0.y); o[2] = f2bf(v0.z); o[3] = f2bf(v0.w);
            o[4] = f2bf(v1.x); o[5] = f2bf(v1.y); o[6] = f2bf(v1.z); o[7] = f2bf(v1.w);
            *(u16x8*)(dstc + r * 8) = o;
        }
    } else {
        const int idx = bx - 256;
        const int nt = idx >> 3, ks = idx & 7;
        const int mi = nt >> 1, cm0 = (nt & 1) * 64;
        const float* Wm = (mi == 0) ? Wl : (mi == 1) ? Wr : (mi == 2) ? Ws1 : We1;

        const int kk_ = t >> 4, cc = (t & 15) << 2;
        #pragma unroll
        for (int u = 0; u < 4; ++u)
            *(float4*)&T[kk_ + 16 * u][cc] =
                *(const float4*)&Wm[(size_t)(ks * 64 + kk_ + 16 * u) * Pc + cm0 + cc];
        __syncthreads();

        const int col = t & 63, c2 = t >> 6;
        #pragma unroll
        for (int h = 0; h < 2; ++h) {
            const int kc = c2 + h * 4;
            u16x8 o;
            #pragma unroll
            for (int i = 0; i < 8; ++i) o[i] = f2bf(T[kc * 8 + i][col]);
            *(u16x8*)(WcatT2 + ((size_t)(nt * 8 + ks) * 8 + kc) * 512 + col * 8) = o;
        }
    }
}

// ---------------------------------------------------------------------------
// mfma_proj3: the (correctness-proven) fused phase-1 as a standalone kernel.
// grid (64 mt2, 8 ny) = 512 blocks -> 2 blocks/CU, 8 waves/CU.
// Tile 32 rows x 64 cols, 4 waves (wm: 16-row half, wn: 32-col half),
// BK=64, double-buffered gload_lds staging, 2 MFMA/wave/kk.
// ny 0..3 -> leftH/rightH (f16); ny 4..7 -> start/end partials -> parts.
// ---------------------------------------------------------------------------
__global__ __launch_bounds__(256) void mfma_proj3(
    const ushort_t* __restrict__ inBF2, const ushort_t* __restrict__ WcatT2,
    const float* __restrict__ bl,
    const float* __restrict__ bs1, const float* __restrict__ Ws2,
    const float* __restrict__ be1, const float* __restrict__ We2,
    ushort_t* __restrict__ leftH, ushort_t* __restrict__ rightH,
    float* __restrict__ parts)
{
    const int mt2 = blockIdx.x, ny = blockIdx.y;
    const int row0 = mt2 * 32;
    const int t = threadIdx.x, w = t >> 6, l = t & 63;
    const int wm = w & 1, wn = w >> 1;
    const int fr = l & 15, fg = l >> 4;

    __shared__ ushort_t As[2][2048];
    __shared__ ushort_t Bs[2][4096];
    __shared__ float red[64];

    const ushort_t* Atile = inBF2 + (size_t)(mt2 >> 1) * 8 * 4096;
    const int h32 = (mt2 & 1) * 32;
    const ushort_t* Bbase = WcatT2 + (size_t)ny * 8 * 4096;

    f32x4 acc0 = {0.f, 0.f, 0.f, 0.f}, acc1 = {0.f, 0.f, 0.f, 0.f};

#define PSTAGE(BI, KS)                                                         \
    {                                                                          \
        const ushort_t* ga = Atile + (KS) * 4096;                              \
        const ushort_t* gb = Bbase + (KS) * 4096;                              \
        gload_lds16(ga + (2 * w + (l >> 5)) * 512 + (h32 + (l & 31)) * 8,      \
                    &As[BI][w * 512]);                                         \
        gload_lds16(gb + w * 512 + l * 8, &Bs[BI][w * 512]);                   \
        gload_lds16(gb + (w + 4) * 512 + l * 8, &Bs[BI][(w + 4) * 512]);       \
    }

    PSTAGE(0, 0);
    __syncthreads();

    for (int ks = 0; ks < 8; ++ks) {
        const int bi = ks & 1;
        if (ks < 7) PSTAGE(bi ^ 1, ks + 1);
        #pragma unroll
        for (int kk = 0; kk < 2; ++kk) {
            const int kc = kk * 4 + fg;
            bf16x8 a  = *(const bf16x8*)&As[bi][kc * 256 + (wm * 16 + fr) * 8];
            bf16x8 b0 = *(const bf16x8*)&Bs[bi][kc * 512 + (wn * 32 + fr) * 8];
            bf16x8 b1 = *(const bf16x8*)&Bs[bi][kc * 512 + (wn * 32 + 16 + fr) * 8];
            acc0 = __builtin_amdgcn_mfma_f32_16x16x32_bf16(a, b0, acc0, 0, 0, 0);
            acc1 = __builtin_amdgcn_mfma_f32_16x16x32_bf16(a, b1, acc1, 0, 0, 0);
        }
        __syncthreads();
    }
#undef PSTAGE

    const int fq4 = fg << 2;
    if (ny < 4) {
        ushort_t* outp = (ny < 2) ? leftH : rightH;
        const int cb = (ny & 1) * 64 + wn * 32;
        #pragma unroll
        for (int n = 0; n < 2; ++n) {
            const int col = cb + n * 16 + fr;
            const float bv = (ny < 2) ? bl[col] : 0.f;
            const f32x4 av = n ? acc1 : acc0;
            #pragma unroll
            for (int q = 0; q < 4; ++q) {
                float v = av[q] + bv;
                outp[(size_t)(row0 + wm * 16 + fq4 + q) * Pc + col] =
                    __builtin_bit_cast(ushort_t, (_Float16)v);
            }
        }
    } else {
        const int pi = ny - 4;
        const float* b1 = (ny < 6) ? bs1 : be1;
        const float* W2 = (ny < 6) ? Ws2 : We2;
        const int pb = (pi & 1) * 64;
        #pragma unroll
        for (int q = 0; q < 4; ++q) {
            const int cp0 = pb + wn * 32 + fr;
            const int cp1 = pb + wn * 32 + 16 + fr;
            float v = fmaxf(acc0[q] + b1[cp0], 0.f) * W2[cp0]
                    + fmaxf(acc1[q] + b1[cp1], 0.f) * W2[cp1];
            v += __shfl_xor(v, 1);
            v += __shfl_xor(v, 2);
            v += __shfl_xor(v, 4);
            v += __shfl_xor(v, 8);
            if (fr == 0) red[wn * 32 + wm * 16 + fq4 + q] = v;
        }
        __syncthreads();
        if (t < 32) parts[pi * ROWS + row0 + t] = red[t] + red[32 + t];
    }
}

// ---------------------------------------------------------------------------
// bigram v4: v3 structure (64i x 32j tile, thread = 4i x 2j) with uint4
// (b128) LDS reads: 8 p's per step, ~35% fewer LDS-pipe cycles.
// grid (17, 8, 4): jt<16 compute; jt==16 combines start/end partials.
// ---------------------------------------------------------------------------
__global__ __launch_bounds__(256) void bigram_kernel(
    const ushort_t* __restrict__ leftH, const ushort_t* __restrict__ rightH,
    const float* __restrict__ Wo,   const float* __restrict__ bo,
    const float* __restrict__ parts,
    const float* __restrict__ bs2,  const float* __restrict__ be2,
    float* __restrict__ out, float* __restrict__ start_out,
    float* __restrict__ end_out)
{
    const int jt = blockIdx.x, it = blockIdx.y, b = blockIdx.z;
    const int t  = threadIdx.x;

    if (jt == 16) {
        const int base = (b * 8 + it) * 64;
        if (t < 64) {
            const int r = base + t;
            start_out[r] = parts[r] + parts[ROWS + r] + bs2[0];
        } else if (t < 128) {
            const int r = base + t - 64;
            end_out[r] = parts[2 * ROWS + r] + parts[3 * ROWS + r] + be2[0];
        }
        return;
    }

    __shared__ unsigned Lh[32][68];   // j rows, 64 f16-pairs + 16B pad
    __shared__ unsigned Rh[64][68];   // i rows
    __shared__ unsigned woh[64];

    const ushort_t* lp = leftH  + (size_t)(b * Nc + jt * 32) * Pc;
    const ushort_t* rp = rightH + (size_t)(b * Nc + it * 64) * Pc;

    #pragma unroll
    for (int u = 0; u < 2; ++u) {
        int f = t + u * 256, r = f >> 4, c = f & 15;
        *(float4*)&Lh[r][c * 4] = *(const float4*)(lp + (size_t)r * Pc + c * 8);
    }
    #pragma unroll
    for (int u = 0; u < 4; ++u) {
        int f = t + u * 256, r = f >> 4, c = f & 15;
        *(float4*)&Rh[r][c * 4] = *(const float4*)(rp + (size_t)r * Pc + c * 8);
    }
    if (t < 64) woh[t] = packh2(Wo[2 * t], Wo[2 * t + 1]);
    __syncthreads();

    const int jl = t & 15;   // j = jl + 16*jj, jj<2
    const int il = t >> 4;   // i = il + 16*ii, ii<4

    float acc[4][2] = {};
    const h2v hz = {(_Float16)0.f, (_Float16)0.f};

#define DOTH(COMP)                                                       \
    {                                                                    \
        const unsigned wu = w4.COMP;                                     \
        h2v lv[2], rv[4];                                                \
        lv[0] = __builtin_bit_cast(h2v, l4[0].COMP);                     \
        lv[1] = __builtin_bit_cast(h2v, l4[1].COMP);                     \
        rv[0] = __builtin_bit_cast(h2v, r4[0].COMP);                     \
        rv[1] = __builtin_bit_cast(h2v, r4[1].COMP);                     \
        rv[2] = __builtin_bit_cast(h2v, r4[2].COMP);                     \
        rv[3] = __builtin_bit_cast(h2v, r4[3].COMP);                     \
        _Pragma("unroll") for (int ii = 0; ii < 4; ++ii)                 \
        _Pragma("unroll") for (int jj = 0; jj < 2; ++jj) {               \
            h2v sum = lv[jj] + rv[ii];                                   \
            sum = __builtin_elementwise_max(sum, hz);                    \
            unsigned su = __builtin_bit_cast(unsigned, sum);             \
            asm("v_dot2_f32_f16 %0, %1, %2, %0"                          \
                : "+v"(acc[ii][jj]) : "v"(su), "v"(wu));                 \
        }                                                                \
    }

    #pragma unroll 4
    for (int s4 = 0; s4 < 16; ++s4) {        // 8 p's per step
        uint4 w4 = *(const uint4*)&woh[4 * s4];
        uint4 l4[2], r4[4];
        #pragma unroll
        for (int jj = 0; jj < 2; ++jj) l4[jj] = *(const uint4*)&Lh[jl + 16 * jj][4 * s4];
        #pragma unroll
        for (int ii = 0; ii < 4; ++ii) r4[ii] = *(const uint4*)&Rh[il + 16 * ii][4 * s4];
        DOTH(x) DOTH(y) DOTH(z) DOTH(w)
    }
#undef DOTH

    const float bias = bo[0];
    #pragma unroll
    for (int ii = 0; ii < 4; ++ii) {
        #pragma unroll
        for (int jj = 0; jj < 2; ++jj) {
            const int gi = it * 64 + il + 16 * ii;
            const int gj = jt * 32 + jl + 16 * jj;
            out[((size_t)b * Nc + gi) * Nc + gj] = acc[ii][jj] + bias;
        }
    }
}

extern "C" void kernel_launch(void* const* d_in, const int* in_sizes, int n_in,
                              void* d_out, int out_size, void* d_ws, size_t ws_size,
                              hipStream_t stream) {
    const float* input = (const float*)d_in[0];
    const float* Wl  = (const float*)d_in[1];
    const float* bl  = (const float*)d_in[2];
    const float* Wr  = (const float*)d_in[3];
    const float* Wo  = (const float*)d_in[4];
    const float* bo  = (const float*)d_in[5];
    const float* Ws1 = (const float*)d_in[6];
    const float* bs1 = (const float*)d_in[7];
    const float* Ws2 = (const float*)d_in[8];
    const float* bs2 = (const float*)d_in[9];
    const float* We1 = (const float*)d_in[10];
    const float* be1 = (const float*)d_in[11];
    const float* We2 = (const float*)d_in[12];
    const float* be2 = (const float*)d_in[13];

    float* out    = (float*)d_out;
    float* bigram = out;
    float* start  = out + (size_t)Bc * Nc * Nc;
    float* end    = start + (size_t)Bc * Nc;

    ushort_t* leftH  = (ushort_t*)d_ws;                  // 2048*128 f16
    ushort_t* rightH = leftH + (size_t)ROWS * Pc;        // 2048*128 f16
    float* parts     = (float*)(rightH + (size_t)ROWS * Pc);   // 4*2048 f32
    ushort_t* inBF2  = (ushort_t*)(parts + 4 * ROWS);    // 2048*512 bf16 (tiled)
    ushort_t* WcatT2 = inBF2 + (size_t)ROWS * Dc;        // 512*512 bf16 (tiled)

    convert_kernel<<<320, 256, 0, stream>>>(input, Wl, Wr, Ws1, We1, inBF2, WcatT2);

    mfma_proj3<<<dim3(64, 8), 256, 0, stream>>>(
        inBF2, WcatT2, bl, bs1, Ws2, be1, We2, leftH, rightH, parts);

    bigram_kernel<<<dim3(17, 8, 4), 256, 0, stream>>>(
        leftH, rightH, Wo, bo, parts, bs2, be2, bigram, start, end);
}

// Round 8
// 31.369 us; speedup vs baseline: 8.2652x; 1.0021x over previous
//
#include <hip/hip_runtime.h>

typedef unsigned short ushort_t;
using f32x4  = __attribute__((ext_vector_type(4))) float;
using bf16x8 = __attribute__((ext_vector_type(8))) short;
using u16x8  = __attribute__((ext_vector_type(8))) unsigned short;
using h2v    = __attribute__((ext_vector_type(2))) _Float16;

constexpr int Bc = 4;
constexpr int Nc = 512;
constexpr int Dc = 512;
constexpr int Pc = 128;
constexpr int ROWS = Bc * Nc;   // 2048

__device__ inline unsigned short f2bf(float f) {
    unsigned u = __builtin_bit_cast(unsigned, f);
    unsigned r = u + 0x7fffu + ((u >> 16) & 1u);   // RNE
    return (unsigned short)(r >> 16);
}

__device__ inline void gload_lds16(const void* g, void* l) {
    __builtin_amdgcn_global_load_lds(
        (const __attribute__((address_space(1))) unsigned int*)g,
        (__attribute__((address_space(3))) unsigned int*)l, 16, 0, 0);
}

__device__ inline unsigned packh2(float a, float b) {
    unsigned short lo = __builtin_bit_cast(unsigned short, (_Float16)a);
    unsigned short hi = __builtin_bit_cast(unsigned short, (_Float16)b);
    return (unsigned)lo | ((unsigned)hi << 16);
}

// ---------------------------------------------------------------------------
// K0: W-only convert -> WcatT2[nt(8)][ks(8)][kc(8)][col(64)][8] bf16.
// grid 64 = (nt, ks) units. (input conversion now fused into K1.)
// ---------------------------------------------------------------------------
__global__ __launch_bounds__(256) void wconv_kernel(
    const float* __restrict__ Wl,  const float* __restrict__ Wr,
    const float* __restrict__ Ws1, const float* __restrict__ We1,
    ushort_t* __restrict__ WcatT2)
{
    const int bx = blockIdx.x, t = threadIdx.x;
    __shared__ float T[64][68];

    const int nt = bx >> 3, ks = bx & 7;
    const int mi = nt >> 1, cm0 = (nt & 1) * 64;
    const float* Wm = (mi == 0) ? Wl : (mi == 1) ? Wr : (mi == 2) ? Ws1 : We1;

    const int kk_ = t >> 4, cc = (t & 15) << 2;
    #pragma unroll
    for (int u = 0; u < 4; ++u)
        *(float4*)&T[kk_ + 16 * u][cc] =
            *(const float4*)&Wm[(size_t)(ks * 64 + kk_ + 16 * u) * Pc + cm0 + cc];
    __syncthreads();

    const int col = t & 63, c2 = t >> 6;
    #pragma unroll
    for (int h = 0; h < 2; ++h) {
        const int kc = c2 + h * 4;
        u16x8 o;
        #pragma unroll
        for (int i = 0; i < 8; ++i) o[i] = f2bf(T[kc * 8 + i][col]);
        *(u16x8*)(WcatT2 + ((size_t)(nt * 8 + ks) * 8 + kc) * 512 + col * 8) = o;
    }
}

// ---------------------------------------------------------------------------
// K1: proj GEMM with fused input conversion.
// grid (64 mt2, 8 ny) = 512 blocks -> 2 blocks/CU.
// Tile 32r x 64c, BK=64. A: fp32 global -> reg (depth-2 prefetch) -> f2bf ->
// ds_write b128 in fragment order. B: gload_lds from WcatT2 (unchanged).
// Double-buffered LDS, one barrier per K-step. Epilogue as mfma_proj3.
// ---------------------------------------------------------------------------
__global__ __launch_bounds__(256) void mfma_proj4(
    const float* __restrict__ input, const ushort_t* __restrict__ WcatT2,
    const float* __restrict__ bl,
    const float* __restrict__ bs1, const float* __restrict__ Ws2,
    const float* __restrict__ be1, const float* __restrict__ We2,
    ushort_t* __restrict__ leftH, ushort_t* __restrict__ rightH,
    float* __restrict__ parts)
{
    const int mt2 = blockIdx.x, ny = blockIdx.y;
    const int row0 = mt2 * 32;
    const int t = threadIdx.x, w = t >> 6, l = t & 63;
    const int wm = w & 1, wn = w >> 1;
    const int fr = l & 15, fg = l >> 4;

    __shared__ ushort_t As[2][2048];   // [kc(8)][r(32)][8] bf16 fragments
    __shared__ ushort_t Bs[2][4096];   // [kc(8)][col(64)][8]
    __shared__ float red[64];

    const ushort_t* Bbase = WcatT2 + (size_t)ny * 8 * 4096;

    // A staging: thread -> row sr (0..31), k-chunk skc (0..7); 32B fp32 read.
    const int sr = t >> 3, skc = t & 7;
    const float* Ain = input + (size_t)(row0 + sr) * Dc + skc * 8;
    ushort_t* Ad0 = &As[0][skc * 256 + sr * 8];
    ushort_t* Ad1 = &As[1][skc * 256 + sr * 8];

    f32x4 acc0 = {0.f, 0.f, 0.f, 0.f}, acc1 = {0.f, 0.f, 0.f, 0.f};

    float4 aE0, aE1, aO0, aO1;   // ping-pong A registers (even/odd ks)

#define ALOAD(P0, P1, KS)                                     \
    {                                                         \
        const float* s_ = Ain + (KS) * 64;                    \
        P0 = *(const float4*)s_;                              \
        P1 = *(const float4*)(s_ + 4);                        \
    }

#define AWRITE(DST, P0, P1)                                   \
    {                                                         \
        u16x8 o_;                                             \
        o_[0] = f2bf(P0.x); o_[1] = f2bf(P0.y);               \
        o_[2] = f2bf(P0.z); o_[3] = f2bf(P0.w);               \
        o_[4] = f2bf(P1.x); o_[5] = f2bf(P1.y);               \
        o_[6] = f2bf(P1.z); o_[7] = f2bf(P1.w);               \
        *(u16x8*)(DST) = o_;                                  \
    }

#define BSTAGE(BI, KS)                                                   \
    {                                                                    \
        const ushort_t* gb = Bbase + (KS) * 4096;                        \
        gload_lds16(gb + w * 512 + l * 8, &Bs[BI][w * 512]);             \
        gload_lds16(gb + (w + 4) * 512 + l * 8, &Bs[BI][(w + 4) * 512]); \
    }

#define COMPUTE(BI)                                                           \
    {                                                                         \
        _Pragma("unroll") for (int kk = 0; kk < 2; ++kk) {                    \
            const int kc = kk * 4 + fg;                                       \
            bf16x8 a  = *(const bf16x8*)&As[BI][kc * 256 + (wm * 16 + fr) * 8];       \
            bf16x8 b0 = *(const bf16x8*)&Bs[BI][kc * 512 + (wn * 32 + fr) * 8];       \
            bf16x8 b1 = *(const bf16x8*)&Bs[BI][kc * 512 + (wn * 32 + 16 + fr) * 8];  \
            acc0 = __builtin_amdgcn_mfma_f32_16x16x32_bf16(a, b0, acc0, 0, 0, 0);     \
            acc1 = __builtin_amdgcn_mfma_f32_16x16x32_bf16(a, b1, acc1, 0, 0, 0);     \
        }                                                                     \
    }

    // prologue: buffer 0 = ks 0; prefetch A for ks 1.
    ALOAD(aE0, aE1, 0);
    BSTAGE(0, 0);
    AWRITE(Ad0, aE0, aE1);
    ALOAD(aO0, aO1, 1);
    __syncthreads();

    #pragma unroll
    for (int ks2 = 0; ks2 < 8; ks2 += 2) {
        // even step: compute buf 0, stage ks2+1 into buf 1
        BSTAGE(1, ks2 + 1);
        if (ks2 + 2 < 8) ALOAD(aE0, aE1, ks2 + 2);
        COMPUTE(0);
        AWRITE(Ad1, aO0, aO1);
        __syncthreads();
        // odd step: compute buf 1, stage ks2+2 into buf 0
        if (ks2 + 2 < 8) {
            BSTAGE(0, ks2 + 2);
            if (ks2 + 3 < 8) ALOAD(aO0, aO1, ks2 + 3);
        }
        COMPUTE(1);
        if (ks2 + 2 < 8) AWRITE(Ad0, aE0, aE1);
        __syncthreads();
    }
#undef ALOAD
#undef AWRITE
#undef BSTAGE
#undef COMPUTE

    const int fq4 = fg << 2;
    if (ny < 4) {
        ushort_t* outp = (ny < 2) ? leftH : rightH;
        const int cb = (ny & 1) * 64 + wn * 32;
        #pragma unroll
        for (int n = 0; n < 2; ++n) {
            const int col = cb + n * 16 + fr;
            const float bv = (ny < 2) ? bl[col] : 0.f;
            const f32x4 av = n ? acc1 : acc0;
            #pragma unroll
            for (int q = 0; q < 4; ++q) {
                float v = av[q] + bv;
                outp[(size_t)(row0 + wm * 16 + fq4 + q) * Pc + col] =
                    __builtin_bit_cast(ushort_t, (_Float16)v);
            }
        }
    } else {
        const int pi = ny - 4;
        const float* b1 = (ny < 6) ? bs1 : be1;
        const float* W2 = (ny < 6) ? Ws2 : We2;
        const int pb = (pi & 1) * 64;
        #pragma unroll
        for (int q = 0; q < 4; ++q) {
            const int cp0 = pb + wn * 32 + fr;
            const int cp1 = pb + wn * 32 + 16 + fr;
            float v = fmaxf(acc0[q] + b1[cp0], 0.f) * W2[cp0]
                    + fmaxf(acc1[q] + b1[cp1], 0.f) * W2[cp1];
            v += __shfl_xor(v, 1);
            v += __shfl_xor(v, 2);
            v += __shfl_xor(v, 4);
            v += __shfl_xor(v, 8);
            if (fr == 0) red[wn * 32 + wm * 16 + fq4 + q] = v;
        }
        __syncthreads();
        if (t < 32) parts[pi * ROWS + row0 + t] = red[t] + red[32 + t];
    }
}

// ---------------------------------------------------------------------------
// K2: bigram v4 (unchanged). 64i x 32j tile, thread = 4i x 2j, uint4 LDS
// reads (8 p's/step). grid (17,8,4); jt==16 combines start/end partials.
// ---------------------------------------------------------------------------
__global__ __launch_bounds__(256) void bigram_kernel(
    const ushort_t* __restrict__ leftH, const ushort_t* __restrict__ rightH,
    const float* __restrict__ Wo,   const float* __restrict__ bo,
    const float* __restrict__ parts,
    const float* __restrict__ bs2,  const float* __restrict__ be2,
    float* __restrict__ out, float* __restrict__ start_out,
    float* __restrict__ end_out)
{
    const int jt = blockIdx.x, it = blockIdx.y, b = blockIdx.z;
    const int t  = threadIdx.x;

    if (jt == 16) {
        const int base = (b * 8 + it) * 64;
        if (t < 64) {
            const int r = base + t;
            start_out[r] = parts[r] + parts[ROWS + r] + bs2[0];
        } else if (t < 128) {
            const int r = base + t - 64;
            end_out[r] = parts[2 * ROWS + r] + parts[3 * ROWS + r] + be2[0];
        }
        return;
    }

    __shared__ unsigned Lh[32][68];
    __shared__ unsigned Rh[64][68];
    __shared__ unsigned woh[64];

    const ushort_t* lp = leftH  + (size_t)(b * Nc + jt * 32) * Pc;
    const ushort_t* rp = rightH + (size_t)(b * Nc + it * 64) * Pc;

    #pragma unroll
    for (int u = 0; u < 2; ++u) {
        int f = t + u * 256, r = f >> 4, c = f & 15;
        *(float4*)&Lh[r][c * 4] = *(const float4*)(lp + (size_t)r * Pc + c * 8);
    }
    #pragma unroll
    for (int u = 0; u < 4; ++u) {
        int f = t + u * 256, r = f >> 4, c = f & 15;
        *(float4*)&Rh[r][c * 4] = *(const float4*)(rp + (size_t)r * Pc + c * 8);
    }
    if (t < 64) woh[t] = packh2(Wo[2 * t], Wo[2 * t + 1]);
    __syncthreads();

    const int jl = t & 15;
    const int il = t >> 4;

    float acc[4][2] = {};
    const h2v hz = {(_Float16)0.f, (_Float16)0.f};

#define DOTH(COMP)                                                       \
    {                                                                    \
        const unsigned wu = w4.COMP;                                     \
        h2v lv[2], rv[4];                                                \
        lv[0] = __builtin_bit_cast(h2v, l4[0].COMP);                     \
        lv[1] = __builtin_bit_cast(h2v, l4[1].COMP);                     \
        rv[0] = __builtin_bit_cast(h2v, r4[0].COMP);                     \
        rv[1] = __builtin_bit_cast(h2v, r4[1].COMP);                     \
        rv[2] = __builtin_bit_cast(h2v, r4[2].COMP);                     \
        rv[3] = __builtin_bit_cast(h2v, r4[3].COMP);                     \
        _Pragma("unroll") for (int ii = 0; ii < 4; ++ii)                 \
        _Pragma("unroll") for (int jj = 0; jj < 2; ++jj) {               \
            h2v sum = lv[jj] + rv[ii];                                   \
            sum = __builtin_elementwise_max(sum, hz);                    \
            unsigned su = __builtin_bit_cast(unsigned, sum);             \
            asm("v_dot2_f32_f16 %0, %1, %2, %0"                          \
                : "+v"(acc[ii][jj]) : "v"(su), "v"(wu));                 \
        }                                                                \
    }

    #pragma unroll 4
    for (int s4 = 0; s4 < 16; ++s4) {
        uint4 w4 = *(const uint4*)&woh[4 * s4];
        uint4 l4[2], r4[4];
        #pragma unroll
        for (int jj = 0; jj < 2; ++jj) l4[jj] = *(const uint4*)&Lh[jl + 16 * jj][4 * s4];
        #pragma unroll
        for (int ii = 0; ii < 4; ++ii) r4[ii] = *(const uint4*)&Rh[il + 16 * ii][4 * s4];
        DOTH(x) DOTH(y) DOTH(z) DOTH(w)
    }
#undef DOTH

    const float bias = bo[0];
    #pragma unroll
    for (int ii = 0; ii < 4; ++ii) {
        #pragma unroll
        for (int jj = 0; jj < 2; ++jj) {
            const int gi = it * 64 + il + 16 * ii;
            const int gj = jt * 32 + jl + 16 * jj;
            out[((size_t)b * Nc + gi) * Nc + gj] = acc[ii][jj] + bias;
        }
    }
}

extern "C" void kernel_launch(void* const* d_in, const int* in_sizes, int n_in,
                              void* d_out, int out_size, void* d_ws, size_t ws_size,
                              hipStream_t stream) {
    const float* input = (const float*)d_in[0];
    const float* Wl  = (const float*)d_in[1];
    const float* bl  = (const float*)d_in[2];
    const float* Wr  = (const float*)d_in[3];
    const float* Wo  = (const float*)d_in[4];
    const float* bo  = (const float*)d_in[5];
    const float* Ws1 = (const float*)d_in[6];
    const float* bs1 = (const float*)d_in[7];
    const float* Ws2 = (const float*)d_in[8];
    const float* bs2 = (const float*)d_in[9];
    const float* We1 = (const float*)d_in[10];
    const float* be1 = (const float*)d_in[11];
    const float* We2 = (const float*)d_in[12];
    const float* be2 = (const float*)d_in[13];

    float* out    = (float*)d_out;
    float* bigram = out;
    float* start  = out + (size_t)Bc * Nc * Nc;
    float* end    = start + (size_t)Bc * Nc;

    ushort_t* leftH  = (ushort_t*)d_ws;                        // 2048*128 f16
    ushort_t* rightH = leftH + (size_t)ROWS * Pc;              // 2048*128 f16
    float* parts     = (float*)(rightH + (size_t)ROWS * Pc);   // 4*2048 f32
    ushort_t* WcatT2 = (ushort_t*)(parts + 4 * ROWS);          // 512*512 bf16

    wconv_kernel<<<64, 256, 0, stream>>>(Wl, Wr, Ws1, We1, WcatT2);

    mfma_proj4<<<dim3(64, 8), 256, 0, stream>>>(
        input, WcatT2, bl, bs1, Ws2, be1, We2, leftH, rightH, parts);

    bigram_kernel<<<dim3(17, 8, 4), 256, 0, stream>>>(
        leftH, rightH, Wo, bo, parts, bs2, be2, bigram, start, end);
}